// Round 2
// baseline (877.650 us; speedup 1.0000x reference)
//
#include <hip/hip_runtime.h>
#include <hip/hip_bf16.h>

// Problem dims (fixed by setup_inputs)
#define NE  64   // electrons
#define NUP 32   // up electrons (n_up input, fixed 32)
#define NN  16   // nuclei
#define DD  32   // dist features
#define EMB 64   // embedding

__device__ __forceinline__ float ssp(float z) {
    // softplus(z) - log(2), numerically stable
    float a = fabsf(z);
    float t = __expf(-a);
    return fmaxf(z, 0.0f) + __logf(1.0f + t) - 0.6931471805599453f;
}

// ---------------- h subnet: hx = mlp(x) ----------------
__global__ __launch_bounds__(64) void k_hx(
    const float* __restrict__ x, const float* __restrict__ W1,
    const float* __restrict__ b1, const float* __restrict__ W2,
    const float* __restrict__ b2, float* __restrict__ hx)
{
    const int blk = blockIdx.x;      // b*NE + i
    const int e = threadIdx.x;       // feature
    const float* xr = x + (size_t)blk * EMB;   // block-uniform row
    __shared__ float sh[EMB];
    float acc = b1[e];
    #pragma unroll
    for (int k = 0; k < EMB; ++k) acc = fmaf(xr[k], W1[k*EMB + e], acc);
    sh[e] = ssp(acc);
    __syncthreads();
    float acc2 = b2[e];
    #pragma unroll
    for (int k = 0; k < EMB; ++k) acc2 = fmaf(sh[k], W2[k*EMB + e], acc2);
    hx[(size_t)blk*EMB + e] = acc2;
}

// ---------------- electron-pair messages ----------------
// One block per (b,i). Wave w handles j in [16w, 16w+16). lane = feature e.
// label: 0 (same) if spin(i)==spin(j), else 1 (anti).
// output position p = j - (j>i)  (verified against reference pair ordering).
__global__ __launch_bounds__(256) void k_pair(
    const float* __restrict__ edges, const float* __restrict__ wW1,
    const float* __restrict__ wb1,   const float* __restrict__ wW2,
    const float* __restrict__ wb2,   const float* __restrict__ hx,
    float* __restrict__ out_el, float* __restrict__ z_same, float* __restrict__ z_anti)
{
    const int blk = blockIdx.x;
    const int b = blk >> 6;
    const int i = blk & 63;
    const int t = threadIdx.x;
    const int w = t >> 6;       // wave 0..3
    const int e = t & 63;       // feature

    __shared__ __align__(16) float sE[NE][DD];    // 8 KB edge rows
    __shared__ __align__(16) float sH1[NE][EMB];  // 16 KB hidden
    __shared__ __align__(16) float sHx[NE][EMB];  // 16 KB hx[b, all j]
    __shared__ __align__(16) float sZ[4][EMB];    // per-wave z partials

    {   // cooperative stage: edges row-block (2048 f) + hx[b] (4096 f)
        const float4* eb4 = (const float4*)(edges + (size_t)blk * (NE*DD));
        float4* sE4 = (float4*)&sE[0][0];
        sE4[t]       = eb4[t];
        sE4[t + 256] = eb4[t + 256];
        const float4* hx4 = (const float4*)(hx + (size_t)b * (NE*EMB));
        float4* sHx4 = (float4*)&sHx[0][0];
        #pragma unroll
        for (int r = 0; r < 4; ++r) sHx4[t + 256*r] = hx4[t + 256*r];
    }

    const int lab_lo = (i < NUP) ? 0 : 1;        // label for j < 32
    const int lab    = (w < 2) ? lab_lo : (1 - lab_lo);

    // weight columns for (label, e) in registers
    float w1r[DD];
    #pragma unroll
    for (int k = 0; k < DD; ++k) w1r[k] = wW1[(lab*DD + k)*EMB + e];
    float w2r[EMB];
    #pragma unroll
    for (int k = 0; k < EMB; ++k) w2r[k] = wW2[(lab*EMB + k)*EMB + e];
    const float b1v = wb1[lab*EMB + e];
    const float b2v = wb2[lab*EMB + e];

    __syncthreads();

    const int j0 = w * 16;
    // layer 1 for all owned j (including j==i, harmless)
    for (int jj = 0; jj < 16; ++jj) {
        const int j = j0 + jj;
        float acc = b1v;
        const float4* er = (const float4*)&sE[j][0];   // broadcast reads
        #pragma unroll
        for (int k4 = 0; k4 < DD/4; ++k4) {
            float4 v = er[k4];
            acc = fmaf(v.x, w1r[4*k4+0], acc);
            acc = fmaf(v.y, w1r[4*k4+1], acc);
            acc = fmaf(v.z, w1r[4*k4+2], acc);
            acc = fmaf(v.w, w1r[4*k4+3], acc);
        }
        sH1[j][e] = ssp(acc);
    }

    __syncthreads();

    // layer 2 + hx product + z accumulation + store
    float zacc = 0.0f;
    for (int jj = 0; jj < 16; ++jj) {
        const int j = j0 + jj;
        if (j == i) continue;                    // wave-uniform skip
        float acc = b2v;
        const float4* hr = (const float4*)&sH1[j][0];  // broadcast reads
        #pragma unroll
        for (int k4 = 0; k4 < EMB/4; ++k4) {
            float4 v = hr[k4];
            acc = fmaf(v.x, w2r[4*k4+0], acc);
            acc = fmaf(v.y, w2r[4*k4+1], acc);
            acc = fmaf(v.z, w2r[4*k4+2], acc);
            acc = fmaf(v.w, w2r[4*k4+3], acc);
        }
        const float msg = acc * sHx[j][e];
        zacc += msg;
        const int p = j - (j > i ? 1 : 0);
        out_el[((size_t)blk*(NE-1) + p)*EMB + e] = msg;
    }

    sZ[w][e] = zacc;
    __syncthreads();

    if (t < 128) {
        const int which = w;  // 0 => z_same, 1 => z_anti
        // z_same gathers the waves whose label == 0
        const bool take_lo = ((which == 0) == (lab_lo == 0));
        const float v = take_lo ? (sZ[0][e] + sZ[1][e]) : (sZ[2][e] + sZ[3][e]);
        float* dst = (which == 0) ? z_same : z_anti;
        dst[(size_t)blk*EMB + e] = v;
    }
}

// ---------------- nuclear messages ----------------
__global__ __launch_bounds__(256) void k_nuc(
    const float* __restrict__ edges, const float* __restrict__ wW1,
    const float* __restrict__ wb1,   const float* __restrict__ wW2,
    const float* __restrict__ wb2,   const float* __restrict__ Y,
    float* __restrict__ out_nuc, float* __restrict__ z_nuc)
{
    const int blk = blockIdx.x;   // b*NE + i
    const int b = blk >> 6;
    const int t = threadIdx.x;
    const int w = t >> 6;
    const int e = t & 63;

    __shared__ __align__(16) float sE[NN][DD];    // 2 KB
    __shared__ __align__(16) float sH1[NN][EMB];  // 4 KB
    __shared__ __align__(16) float sY[NN][EMB];   // 4 KB
    __shared__ __align__(16) float sZ[4][EMB];

    const float4* eb4 = (const float4*)(edges + (size_t)blk * (NN*DD));
    if (t < NN*DD/4) ((float4*)&sE[0][0])[t] = eb4[t];
    const float4* y4 = (const float4*)(Y + (size_t)b * (NN*EMB));
    ((float4*)&sY[0][0])[t] = y4[t];  // 256 float4 exactly

    float w1r[DD];
    #pragma unroll
    for (int k = 0; k < DD; ++k) w1r[k] = wW1[(2*DD + k)*EMB + e];
    float w2r[EMB];
    #pragma unroll
    for (int k = 0; k < EMB; ++k) w2r[k] = wW2[(2*EMB + k)*EMB + e];
    const float b1v = wb1[2*EMB + e];
    const float b2v = wb2[2*EMB + e];

    __syncthreads();

    const int n0 = w * 4;
    for (int nn = 0; nn < 4; ++nn) {
        const int n = n0 + nn;
        float acc = b1v;
        const float4* er = (const float4*)&sE[n][0];
        #pragma unroll
        for (int k4 = 0; k4 < DD/4; ++k4) {
            float4 v = er[k4];
            acc = fmaf(v.x, w1r[4*k4+0], acc);
            acc = fmaf(v.y, w1r[4*k4+1], acc);
            acc = fmaf(v.z, w1r[4*k4+2], acc);
            acc = fmaf(v.w, w1r[4*k4+3], acc);
        }
        sH1[n][e] = ssp(acc);
    }
    __syncthreads();

    float zacc = 0.0f;
    for (int nn = 0; nn < 4; ++nn) {
        const int n = n0 + nn;
        float acc = b2v;
        const float4* hr = (const float4*)&sH1[n][0];
        #pragma unroll
        for (int k4 = 0; k4 < EMB/4; ++k4) {
            float4 v = hr[k4];
            acc = fmaf(v.x, w2r[4*k4+0], acc);
            acc = fmaf(v.y, w2r[4*k4+1], acc);
            acc = fmaf(v.z, w2r[4*k4+2], acc);
            acc = fmaf(v.w, w2r[4*k4+3], acc);
        }
        const float msg = acc * sY[n][e];
        zacc += msg;
        out_nuc[((size_t)blk*NN + n)*EMB + e] = msg;
    }
    sZ[w][e] = zacc;
    __syncthreads();
    if (t < 64) z_nuc[(size_t)blk*EMB + e] = sZ[0][e] + sZ[1][e] + sZ[2][e] + sZ[3][e];
}

// ---------------- update: g0(z_same)+g1(z_anti)+g2(z_nuc) ----------------
__global__ __launch_bounds__(64) void k_update(
    const float* __restrict__ z_same, const float* __restrict__ z_anti,
    const float* __restrict__ z_nuc,  const float* __restrict__ gW1,
    const float* __restrict__ gb1,    const float* __restrict__ gW2,
    const float* __restrict__ gb2,    float* __restrict__ upd)
{
    const int blk = blockIdx.x;   // b*NE + i
    const int e = threadIdx.x;
    __shared__ float sh[EMB];
    float out = 0.0f;
    const float* zs0 = z_same + (size_t)blk*EMB;
    const float* zs1 = z_anti + (size_t)blk*EMB;
    const float* zs2 = z_nuc  + (size_t)blk*EMB;
    #pragma unroll
    for (int l = 0; l < 3; ++l) {
        const float* z = (l == 0) ? zs0 : (l == 1) ? zs1 : zs2;  // static after unroll
        float acc = gb1[l*EMB + e];
        #pragma unroll
        for (int k = 0; k < EMB; ++k) acc = fmaf(z[k], gW1[(l*EMB + k)*EMB + e], acc);
        const float h = ssp(acc);
        __syncthreads();
        sh[e] = h;
        __syncthreads();
        float acc2 = gb2[l*EMB + e];
        #pragma unroll
        for (int k = 0; k < EMB; ++k) acc2 = fmaf(sh[k], gW2[(l*EMB + k)*EMB + e], acc2);
        out += acc2;
    }
    upd[(size_t)blk*EMB + e] = out;
}

extern "C" void kernel_launch(void* const* d_in, const int* in_sizes, int n_in,
                              void* d_out, int out_size, void* d_ws, size_t ws_size,
                              hipStream_t stream)
{
    const float* x   = (const float*)d_in[0];
    const float* Y   = (const float*)d_in[1];
    const float* eE  = (const float*)d_in[2];
    const float* eN  = (const float*)d_in[3];
    const float* wW1 = (const float*)d_in[4];
    const float* wb1 = (const float*)d_in[5];
    const float* wW2 = (const float*)d_in[6];
    const float* wb2 = (const float*)d_in[7];
    const float* hW1 = (const float*)d_in[8];
    const float* hb1 = (const float*)d_in[9];
    const float* hW2 = (const float*)d_in[10];
    const float* hb2 = (const float*)d_in[11];
    const float* gW1 = (const float*)d_in[12];
    const float* gb1 = (const float*)d_in[13];
    const float* gW2 = (const float*)d_in[14];
    const float* gb2 = (const float*)d_in[15];

    const int B   = in_sizes[0] / (NE * EMB);   // 256
    const int nbi = B * NE;                      // 16384

    // workspace: hx | z_same | z_anti | z_nuc  (4 * nbi * EMB floats = 16 MB)
    float* hx     = (float*)d_ws;
    float* z_same = hx     + (size_t)nbi * EMB;
    float* z_anti = z_same + (size_t)nbi * EMB;
    float* z_nuc  = z_anti + (size_t)nbi * EMB;

    // outputs: update | messages_el | messages_nuc (concatenated flat)
    float* upd     = (float*)d_out;
    float* out_el  = upd    + (size_t)nbi * EMB;
    float* out_nuc = out_el + (size_t)nbi * (NE-1) * EMB;

    k_hx    <<<nbi,  64, 0, stream>>>(x, hW1, hb1, hW2, hb2, hx);
    k_pair  <<<nbi, 256, 0, stream>>>(eE, wW1, wb1, wW2, wb2, hx, out_el, z_same, z_anti);
    k_nuc   <<<nbi, 256, 0, stream>>>(eN, wW1, wb1, wW2, wb2, Y, out_nuc, z_nuc);
    k_update<<<nbi,  64, 0, stream>>>(z_same, z_anti, z_nuc, gW1, gb1, gW2, gb2, upd);
}

// Round 5
// 819.322 us; speedup vs baseline: 1.0712x; 1.0712x over previous
//
#include <hip/hip_runtime.h>
#include <hip/hip_bf16.h>

// Problem dims (fixed by setup_inputs)
#define NE  64   // electrons
#define NUP 32   // up electrons
#define NN  16   // nuclei
#define DD  32   // dist features
#define EMB 64   // embedding

__device__ __forceinline__ float ssp(float z) {
    float a = fabsf(z);
    float t = __expf(-a);
    return fmaxf(z, 0.0f) + __logf(1.0f + t) - 0.6931471805599453f;
}

// ---------------- h subnet, 4 rows per block ----------------
__global__ __launch_bounds__(256) void k_hx(
    const float* __restrict__ x, const float* __restrict__ W1,
    const float* __restrict__ b1, const float* __restrict__ W2,
    const float* __restrict__ b2, float* __restrict__ hx)
{
    const int t = threadIdx.x;
    const int w = t >> 6;        // wave = row within block
    const int e = t & 63;        // feature
    const size_t row0 = (size_t)blockIdx.x * 4;

    __shared__ __align__(16) float sX[4][EMB];   // 4 input rows
    __shared__ float sh[4][EMB];                 // hidden relay

    if (t < 64) ((float4*)&sX[0][0])[t] = ((const float4*)(x + row0*EMB))[t];
    __syncthreads();

    float acc = b1[e];
    #pragma unroll
    for (int k = 0; k < EMB; ++k) acc = fmaf(sX[w][k], W1[k*EMB + e], acc);
    sh[w][e] = ssp(acc);
    __syncthreads();
    float acc2 = b2[e];
    #pragma unroll
    for (int k = 0; k < EMB; ++k) acc2 = fmaf(sh[w][k], W2[k*EMB + e], acc2);
    hx[(row0 + w)*EMB + e] = acc2;
}

// ---------------- fused: pair messages + nuc messages + update ----------------
// One block per (b,i). 4 waves. lane = feature e.
__global__ __launch_bounds__(256, 3) void k_main(
    const float* __restrict__ eE,  const float* __restrict__ eN,
    const float* __restrict__ wW1, const float* __restrict__ wb1,
    const float* __restrict__ wW2, const float* __restrict__ wb2,
    const float* __restrict__ Y,   const float* __restrict__ hx,
    const float* __restrict__ gW1, const float* __restrict__ gb1,
    const float* __restrict__ gW2, const float* __restrict__ gb2,
    float* __restrict__ out_el, float* __restrict__ out_nuc, float* __restrict__ upd)
{
    const int blk = blockIdx.x;
    const int b = blk >> 6;
    const int i = blk & 63;
    const int t = threadIdx.x;
    const int w = t >> 6;       // wave 0..3
    const int e = t & 63;       // feature

    __shared__ __align__(16) float sE[NE][DD];    // 8 KB
    __shared__ __align__(16) float sH1[NE][EMB];  // 16 KB (pair hidden; rows 0..15 reused for nuc)
    __shared__ __align__(16) float sHx[NE][EMB];  // 16 KB
    __shared__ __align__(16) float sEN[NN][DD];   // 2 KB
    __shared__ __align__(16) float sY[NN][EMB];   // 4 KB
    __shared__ __align__(16) float sZp[4][EMB];   // per-wave z partials (pair, then nuc)
    __shared__ float sZS[EMB], sZA[EMB], sZN[EMB];
    __shared__ float sGH[3][EMB];
    __shared__ float sU[3][EMB];

    {   // cooperative staging
        const float4* eb4 = (const float4*)(eE + (size_t)blk * (NE*DD));
        float4* sE4 = (float4*)&sE[0][0];
        sE4[t]       = eb4[t];
        sE4[t + 256] = eb4[t + 256];
        const float4* hx4 = (const float4*)(hx + (size_t)b * (NE*EMB));
        float4* sHx4 = (float4*)&sHx[0][0];
        #pragma unroll
        for (int r = 0; r < 4; ++r) sHx4[t + 256*r] = hx4[t + 256*r];
        const float4* en4 = (const float4*)(eN + (size_t)blk * (NN*DD));
        if (t < 128) ((float4*)&sEN[0][0])[t] = en4[t];
        const float4* y4 = (const float4*)(Y + (size_t)b * (NN*EMB));
        ((float4*)&sY[0][0])[t] = y4[t];   // exactly 256 float4
    }

    const int lab_lo = (i < NUP) ? 0 : 1;
    const int lab    = (w < 2) ? lab_lo : (1 - lab_lo);

    // -------- pair phase: weight columns in registers --------
    float w1r[DD];
    #pragma unroll
    for (int k = 0; k < DD; ++k) w1r[k] = wW1[(lab*DD + k)*EMB + e];
    float w2r[EMB];
    #pragma unroll
    for (int k = 0; k < EMB; ++k) w2r[k] = wW2[(lab*EMB + k)*EMB + e];
    const float b1v = wb1[lab*EMB + e];
    const float b2v = wb2[lab*EMB + e];

    __syncthreads();

    const int j0 = w * 16;
    for (int jj = 0; jj < 16; ++jj) {            // layer 1
        const int j = j0 + jj;
        float acc = b1v;
        const float4* er = (const float4*)&sE[j][0];
        #pragma unroll
        for (int k4 = 0; k4 < DD/4; ++k4) {
            float4 v = er[k4];
            acc = fmaf(v.x, w1r[4*k4+0], acc);
            acc = fmaf(v.y, w1r[4*k4+1], acc);
            acc = fmaf(v.z, w1r[4*k4+2], acc);
            acc = fmaf(v.w, w1r[4*k4+3], acc);
        }
        sH1[j][e] = ssp(acc);
    }
    __syncthreads();

    float zacc = 0.0f;
    for (int jj = 0; jj < 16; ++jj) {            // layer 2 + hx product
        const int j = j0 + jj;
        if (j == i) continue;                    // wave-uniform
        float acc = b2v;
        const float4* hr = (const float4*)&sH1[j][0];
        #pragma unroll
        for (int k4 = 0; k4 < EMB/4; ++k4) {
            float4 v = hr[k4];
            acc = fmaf(v.x, w2r[4*k4+0], acc);
            acc = fmaf(v.y, w2r[4*k4+1], acc);
            acc = fmaf(v.z, w2r[4*k4+2], acc);
            acc = fmaf(v.w, w2r[4*k4+3], acc);
        }
        const float msg = acc * sHx[j][e];
        zacc += msg;
        const int p = j - (j > i ? 1 : 0);
        out_el[((size_t)blk*(NE-1) + p)*EMB + e] = msg;
    }
    sZp[w][e] = zacc;

    // -------- nuc phase: reload weight columns for label 2 --------
    #pragma unroll
    for (int k = 0; k < DD; ++k) w1r[k] = wW1[(2*DD + k)*EMB + e];
    #pragma unroll
    for (int k = 0; k < EMB; ++k) w2r[k] = wW2[(2*EMB + k)*EMB + e];
    const float b1n = wb1[2*EMB + e];
    const float b2n = wb2[2*EMB + e];

    __syncthreads();

    // combine pair partials into z_same / z_anti
    if (t < 128) {
        const int which = w;  // 0 => same, 1 => anti
        const bool take_lo = ((which == 0) == (lab_lo == 0));
        const float v = take_lo ? (sZp[0][e] + sZp[1][e]) : (sZp[2][e] + sZp[3][e]);
        float* dst = (which == 0) ? sZS : sZA;
        dst[e] = v;
    }

    // nuc layer 1 (each wave: 4 nuclei), writes sH1 rows 0..15
    const int n0 = w * 4;
    for (int nn = 0; nn < 4; ++nn) {
        const int n = n0 + nn;
        float acc = b1n;
        const float4* er = (const float4*)&sEN[n][0];
        #pragma unroll
        for (int k4 = 0; k4 < DD/4; ++k4) {
            float4 v = er[k4];
            acc = fmaf(v.x, w1r[4*k4+0], acc);
            acc = fmaf(v.y, w1r[4*k4+1], acc);
            acc = fmaf(v.z, w1r[4*k4+2], acc);
            acc = fmaf(v.w, w1r[4*k4+3], acc);
        }
        sH1[n][e] = ssp(acc);
    }
    __syncthreads();

    float zn = 0.0f;
    for (int nn = 0; nn < 4; ++nn) {
        const int n = n0 + nn;
        float acc = b2n;
        const float4* hr = (const float4*)&sH1[n][0];
        #pragma unroll
        for (int k4 = 0; k4 < EMB/4; ++k4) {
            float4 v = hr[k4];
            acc = fmaf(v.x, w2r[4*k4+0], acc);
            acc = fmaf(v.y, w2r[4*k4+1], acc);
            acc = fmaf(v.z, w2r[4*k4+2], acc);
            acc = fmaf(v.w, w2r[4*k4+3], acc);
        }
        const float msg = acc * sY[n][e];
        zn += msg;
        out_nuc[((size_t)blk*NN + n)*EMB + e] = msg;
    }
    sZp[w][e] = zn;   // safe: previous sZp consumers finished before last sync
    __syncthreads();
    if (t < 64) sZN[e] = sZp[0][e] + sZp[1][e] + sZp[2][e] + sZp[3][e];
    __syncthreads();

    // -------- update phase: waves 0..2 run the three g subnets --------
    if (w < 3) {
        const float* z = (w == 0) ? sZS : (w == 1) ? sZA : sZN;
        float acc = gb1[w*EMB + e];
        #pragma unroll
        for (int k = 0; k < EMB; ++k) acc = fmaf(z[k], gW1[(w*EMB + k)*EMB + e], acc);
        sGH[w][e] = ssp(acc);
    }
    __syncthreads();
    if (w < 3) {
        float acc2 = gb2[w*EMB + e];
        #pragma unroll
        for (int k = 0; k < EMB; ++k) acc2 = fmaf(sGH[w][k], gW2[(w*EMB + k)*EMB + e], acc2);
        sU[w][e] = acc2;
    }
    __syncthreads();
    if (t < 64) upd[(size_t)blk*EMB + e] = sU[0][e] + sU[1][e] + sU[2][e];
}

extern "C" void kernel_launch(void* const* d_in, const int* in_sizes, int n_in,
                              void* d_out, int out_size, void* d_ws, size_t ws_size,
                              hipStream_t stream)
{
    const float* x   = (const float*)d_in[0];
    const float* Y   = (const float*)d_in[1];
    const float* eE  = (const float*)d_in[2];
    const float* eN  = (const float*)d_in[3];
    const float* wW1 = (const float*)d_in[4];
    const float* wb1 = (const float*)d_in[5];
    const float* wW2 = (const float*)d_in[6];
    const float* wb2 = (const float*)d_in[7];
    const float* hW1 = (const float*)d_in[8];
    const float* hb1 = (const float*)d_in[9];
    const float* hW2 = (const float*)d_in[10];
    const float* hb2 = (const float*)d_in[11];
    const float* gW1 = (const float*)d_in[12];
    const float* gb1 = (const float*)d_in[13];
    const float* gW2 = (const float*)d_in[14];
    const float* gb2 = (const float*)d_in[15];

    const int B   = in_sizes[0] / (NE * EMB);   // 256
    const int nbi = B * NE;                      // 16384

    float* hx = (float*)d_ws;                    // 4 MB workspace

    float* upd     = (float*)d_out;
    float* out_el  = upd    + (size_t)nbi * EMB;
    float* out_nuc = out_el + (size_t)nbi * (NE-1) * EMB;

    k_hx  <<<nbi/4, 256, 0, stream>>>(x, hW1, hb1, hW2, hb2, hx);
    k_main<<<nbi,   256, 0, stream>>>(eE, eN, wW1, wb1, wW2, wb2, Y, hx,
                                      gW1, gb1, gW2, gb2, out_el, out_nuc, upd);
}

// Round 10
// 676.343 us; speedup vs baseline: 1.2976x; 1.2114x over previous
//
#include <hip/hip_runtime.h>
#include <hip/hip_bf16.h>

#define NE  64
#define NUP 32
#define NN  16
#define DD  32
#define EMB 64

typedef __attribute__((ext_vector_type(8))) short bf16x8;
typedef __attribute__((ext_vector_type(4))) float f32x4;

// frag-buffer offsets (ushort units) within ws after the 4MB hx region
#define W1H_OFF  0
#define W1L_OFF  6144
#define W2H_OFF  12288
#define W2L_OFF  24576
#define HW1H_OFF 36864
#define HW1L_OFF 40960
#define HW2H_OFF 45056
#define HW2L_OFF 49152

__device__ __forceinline__ float ssp(float z) {
    float a = fabsf(z);
    float t = __expf(-a);
    return fmaxf(z, 0.0f) + __logf(1.0f + t) - 0.6931471805599453f;
}

__device__ __forceinline__ void split1(float x, unsigned short& hi, unsigned short& lo) {
    unsigned u = __float_as_uint(x);
    hi = (unsigned short)(u >> 16);
    float r = x - __uint_as_float(u & 0xFFFF0000u);   // exact
    lo = (unsigned short)(__float_as_uint(r) >> 16);
}

__device__ __forceinline__ void split8(const float* v, bf16x8& hi, bf16x8& lo) {
    #pragma unroll
    for (int j = 0; j < 8; ++j) {
        unsigned u = __float_as_uint(v[j]);
        hi[j] = (short)(u >> 16);
        float r = v[j] - __uint_as_float(u & 0xFFFF0000u);
        lo[j] = (short)(__float_as_uint(r) >> 16);
    }
}

__device__ __forceinline__ bf16x8 ldfrag(const unsigned short* p) {
    return *(const bf16x8*)p;
}

#define MFMA3(acc, ah, al, bh, bl)                                            \
    acc = __builtin_amdgcn_mfma_f32_16x16x32_bf16(al, bh, acc, 0, 0, 0);      \
    acc = __builtin_amdgcn_mfma_f32_16x16x32_bf16(ah, bl, acc, 0, 0, 0);      \
    acc = __builtin_amdgcn_mfma_f32_16x16x32_bf16(ah, bh, acc, 0, 0, 0);

// -------- pack weights into MFMA-frag-ordered hi/lo bf16 (runs every launch, ~2us) --------
__global__ __launch_bounds__(256) void k_wsplit(
    const float* __restrict__ wW1, const float* __restrict__ wW2,
    const float* __restrict__ hW1, const float* __restrict__ hW2,
    unsigned short* __restrict__ fr)
{
    const int idx = blockIdx.x * 256 + threadIdx.x;
    // W1 frags: [lab][nt][lane][8], 6144 elems
    if (idx < 6144) {
        int j = idx & 7, l = (idx >> 3) & 63, nt = (idx >> 9) & 3, lab = idx >> 11;
        int k = (l >> 4) * 8 + j, n = nt * 16 + (l & 15);
        unsigned short h, lo2; split1(wW1[lab*DD*EMB + k*EMB + n], h, lo2);
        fr[W1H_OFF + idx] = h; fr[W1L_OFF + idx] = lo2;
    }
    // W2 frags: [lab][nt][kc][lane][8], 12288 elems
    if (idx < 12288) {
        int j = idx & 7, l = (idx >> 3) & 63, kc = (idx >> 9) & 1, nt = (idx >> 10) & 3, lab = idx >> 12;
        int k = kc*32 + (l >> 4)*8 + j, n = nt*16 + (l & 15);
        unsigned short h, lo2; split1(wW2[lab*EMB*EMB + k*EMB + n], h, lo2);
        fr[W2H_OFF + idx] = h; fr[W2L_OFF + idx] = lo2;
    }
    // hW1/hW2 frags: [nt][kc][lane][8], 4096 elems each
    if (idx < 4096) {
        int j = idx & 7, l = (idx >> 3) & 63, kc = (idx >> 9) & 1, nt = idx >> 10;
        int k = kc*32 + (l >> 4)*8 + j, n = nt*16 + (l & 15);
        unsigned short h, lo2;
        split1(hW1[k*EMB + n], h, lo2);
        fr[HW1H_OFF + idx] = h; fr[HW1L_OFF + idx] = lo2;
        split1(hW2[k*EMB + n], h, lo2);
        fr[HW2H_OFF + idx] = h; fr[HW2L_OFF + idx] = lo2;
    }
}

// -------- h subnet via MFMA: 64 rows per block, wave = M-tile --------
__global__ __launch_bounds__(256) void k_hx(
    const float* __restrict__ x, const float* __restrict__ hb1,
    const float* __restrict__ hb2, const unsigned short* __restrict__ fr,
    float* __restrict__ hx)
{
    const int t = threadIdx.x;
    const int w = t >> 6, lane = t & 63;
    const int lrow = lane & 15, g = lane >> 4, lk8 = g * 8;
    const size_t base = (size_t)blockIdx.x * 64;

    __shared__ __align__(16) unsigned short sH1h[64*72], sH1l[64*72];

    bf16x8 ah[2], al[2];
    #pragma unroll
    for (int kc = 0; kc < 2; ++kc) {
        float v[8];
        const float* xr = x + (base + 16*w + lrow) * EMB + kc*32 + lk8;
        *(float4*)v = *(const float4*)xr; *(float4*)(v+4) = *(const float4*)(xr+4);
        split8(v, ah[kc], al[kc]);
    }
    #pragma unroll
    for (int nt = 0; nt < 4; ++nt) {
        f32x4 acc = {0.f,0.f,0.f,0.f};
        #pragma unroll
        for (int kc = 0; kc < 2; ++kc) {
            bf16x8 bh = ldfrag(fr + HW1H_OFF + ((nt*2 + kc)*64 + lane)*8);
            bf16x8 bl = ldfrag(fr + HW1L_OFF + ((nt*2 + kc)*64 + lane)*8);
            MFMA3(acc, ah[kc], al[kc], bh, bl);
        }
        const float b1v = hb1[nt*16 + lrow];
        #pragma unroll
        for (int r = 0; r < 4; ++r) {
            float h = ssp(acc[r] + b1v);
            unsigned short hi, lo; split1(h, hi, lo);
            const int row = 16*w + g*4 + r, col = nt*16 + lrow;
            sH1h[row*72 + col] = hi; sH1l[row*72 + col] = lo;
        }
    }
    __syncthreads();
    #pragma unroll
    for (int kc = 0; kc < 2; ++kc) {
        const int off = (16*w + lrow)*72 + kc*32 + lk8;
        ah[kc] = *(const bf16x8*)&sH1h[off];
        al[kc] = *(const bf16x8*)&sH1l[off];
    }
    #pragma unroll
    for (int nt = 0; nt < 4; ++nt) {
        f32x4 acc = {0.f,0.f,0.f,0.f};
        #pragma unroll
        for (int kc = 0; kc < 2; ++kc) {
            bf16x8 bh = ldfrag(fr + HW2H_OFF + ((nt*2 + kc)*64 + lane)*8);
            bf16x8 bl = ldfrag(fr + HW2L_OFF + ((nt*2 + kc)*64 + lane)*8);
            MFMA3(acc, ah[kc], al[kc], bh, bl);
        }
        const float b2v = hb2[nt*16 + lrow];
        #pragma unroll
        for (int r = 0; r < 4; ++r) {
            const size_t grow = base + 16*w + g*4 + r;
            hx[grow*EMB + nt*16 + lrow] = acc[r] + b2v;
        }
    }
}

// -------- fused pair + nuc + update, MFMA core. One block per (b,i). --------
__global__ __launch_bounds__(256, 3) void k_main(
    const float* __restrict__ eE,  const float* __restrict__ eN,
    const float* __restrict__ wb1, const float* __restrict__ wb2,
    const float* __restrict__ Y,   const float* __restrict__ hx,
    const float* __restrict__ gW1, const float* __restrict__ gb1,
    const float* __restrict__ gW2, const float* __restrict__ gb2,
    const unsigned short* __restrict__ fr,
    float* __restrict__ out_el, float* __restrict__ out_nuc, float* __restrict__ upd)
{
    const int blk = blockIdx.x;
    const int b = blk >> 6, i = blk & 63;
    const int t = threadIdx.x;
    const int w = t >> 6, lane = t & 63;
    const int lrow = lane & 15, g = lane >> 4, lk8 = g * 8;

    __shared__ __align__(16) unsigned short sH1h[64*72], sH1l[64*72]; // 18.4 KB
    __shared__ __align__(16) float sHx[NE*EMB];                       // 16 KB
    __shared__ __align__(16) float sY[NN*EMB];                        // 4 KB
    __shared__ float sZw[4][EMB];
    __shared__ float sZS[EMB], sZA[EMB], sZN[EMB];
    __shared__ float sGH[3][EMB], sU[3][EMB];

    {   // stage hx[b] (f32) and Y[b]
        const float4* hx4 = (const float4*)(hx + (size_t)b * (NE*EMB));
        float4* d4 = (float4*)sHx;
        #pragma unroll
        for (int r = 0; r < 4; ++r) d4[t + 256*r] = hx4[t + 256*r];
        ((float4*)sY)[t] = ((const float4*)(Y + (size_t)b * (NN*EMB)))[t];
    }

    const int lab_lo = (i < NUP) ? 0 : 1;
    const int lab = ((w < 2) == (i < NUP)) ? 0 : 1;   // wave-uniform label

    // ---- pair layer 1 ----
    {
        float v[8];
        const float* er = eE + (size_t)blk*(NE*DD) + (16*w + lrow)*DD + lk8;
        *(float4*)v = *(const float4*)er; *(float4*)(v+4) = *(const float4*)(er+4);
        bf16x8 eh, el; split8(v, eh, el);
        #pragma unroll
        for (int nt = 0; nt < 4; ++nt) {
            bf16x8 bh = ldfrag(fr + W1H_OFF + ((lab*4 + nt)*64 + lane)*8);
            bf16x8 bl = ldfrag(fr + W1L_OFF + ((lab*4 + nt)*64 + lane)*8);
            f32x4 acc = {0.f,0.f,0.f,0.f};
            MFMA3(acc, eh, el, bh, bl);
            const float b1v = wb1[lab*EMB + nt*16 + lrow];
            #pragma unroll
            for (int r = 0; r < 4; ++r) {
                float h = ssp(acc[r] + b1v);
                unsigned short hi, lo; split1(h, hi, lo);
                const int row = 16*w + g*4 + r, col = nt*16 + lrow;
                sH1h[row*72 + col] = hi; sH1l[row*72 + col] = lo;
            }
        }
    }
    __syncthreads();   // sH1 + sHx/sY ready

    // ---- pair layer 2 + epilogue ----
    {
        bf16x8 ah[2], al[2];
        #pragma unroll
        for (int kc = 0; kc < 2; ++kc) {
            const int off = (16*w + lrow)*72 + kc*32 + lk8;
            ah[kc] = *(const bf16x8*)&sH1h[off];
            al[kc] = *(const bf16x8*)&sH1l[off];
        }
        #pragma unroll
        for (int nt = 0; nt < 4; ++nt) {
            f32x4 acc = {0.f,0.f,0.f,0.f};
            #pragma unroll
            for (int kc = 0; kc < 2; ++kc) {
                bf16x8 bh = ldfrag(fr + W2H_OFF + (((lab*4 + nt)*2 + kc)*64 + lane)*8);
                bf16x8 bl = ldfrag(fr + W2L_OFF + (((lab*4 + nt)*2 + kc)*64 + lane)*8);
                MFMA3(acc, ah[kc], al[kc], bh, bl);
            }
            const float bv = wb2[lab*EMB + nt*16 + lrow];
            float zp = 0.f;
            #pragma unroll
            for (int r = 0; r < 4; ++r) {
                const int j = 16*w + g*4 + r;
                const int e = nt*16 + lrow;
                const float msg = (acc[r] + bv) * sHx[j*EMB + e];
                if (j != i) {
                    zp += msg;
                    out_el[((size_t)blk*(NE-1) + (j - (j > i ? 1 : 0)))*EMB + e] = msg;
                }
            }
            zp += __shfl_xor(zp, 16);
            zp += __shfl_xor(zp, 32);
            if (lane < 16) sZw[w][nt*16 + lane] = zp;
        }
    }
    __syncthreads();   // all reads of sH1 done; sZw complete

    // ---- nuc layer 1 (reuse sH1 rows 0..15; wave w owns n-tile w) ----
    {
        float v[8];
        const float* er = eN + (size_t)blk*(NN*DD) + lrow*DD + lk8;
        *(float4*)v = *(const float4*)er; *(float4*)(v+4) = *(const float4*)(er+4);
        bf16x8 eh, el; split8(v, eh, el);
        bf16x8 bh = ldfrag(fr + W1H_OFF + ((2*4 + w)*64 + lane)*8);
        bf16x8 bl = ldfrag(fr + W1L_OFF + ((2*4 + w)*64 + lane)*8);
        f32x4 acc = {0.f,0.f,0.f,0.f};
        MFMA3(acc, eh, el, bh, bl);
        const float b1n = wb1[2*EMB + w*16 + lrow];
        #pragma unroll
        for (int r = 0; r < 4; ++r) {
            float h = ssp(acc[r] + b1n);
            unsigned short hi, lo; split1(h, hi, lo);
            const int row = g*4 + r, col = w*16 + lrow;
            sH1h[row*72 + col] = hi; sH1l[row*72 + col] = lo;
        }
    }
    __syncthreads();   // H1n ready

    // ---- nuc layer 2 + epilogue ----
    {
        bf16x8 ah[2], al[2];
        #pragma unroll
        for (int kc = 0; kc < 2; ++kc) {
            const int off = lrow*72 + kc*32 + lk8;
            ah[kc] = *(const bf16x8*)&sH1h[off];
            al[kc] = *(const bf16x8*)&sH1l[off];
        }
        f32x4 acc = {0.f,0.f,0.f,0.f};
        #pragma unroll
        for (int kc = 0; kc < 2; ++kc) {
            bf16x8 bh = ldfrag(fr + W2H_OFF + (((2*4 + w)*2 + kc)*64 + lane)*8);
            bf16x8 bl = ldfrag(fr + W2L_OFF + (((2*4 + w)*2 + kc)*64 + lane)*8);
            MFMA3(acc, ah[kc], al[kc], bh, bl);
        }
        const float b2n = wb2[2*EMB + w*16 + lrow];
        float zp = 0.f;
        #pragma unroll
        for (int r = 0; r < 4; ++r) {
            const int nrow = g*4 + r;
            const int e = w*16 + lrow;
            const float m = (acc[r] + b2n) * sY[nrow*EMB + e];
            zp += m;
            out_nuc[((size_t)blk*NN + nrow)*EMB + e] = m;
        }
        zp += __shfl_xor(zp, 16);
        zp += __shfl_xor(zp, 32);
        if (lane < 16) sZN[w*16 + lane] = zp;
    }
    __syncthreads();

    // ---- combine z_same / z_anti ----
    if (t < 128) {
        const int which = w;   // 0 => same, 1 => anti
        const int e2 = t & 63;
        const bool take_lo = ((which == 0) == (lab_lo == 0));
        const float v = take_lo ? (sZw[0][e2] + sZw[1][e2]) : (sZw[2][e2] + sZw[3][e2]);
        (which == 0 ? sZS : sZA)[e2] = v;
    }
    __syncthreads();

    // ---- update: waves 0..2 run g subnets (f32 VALU) ----
    if (w < 3) {
        const float* z = (w == 0) ? sZS : (w == 1) ? sZA : sZN;
        float acc = gb1[w*EMB + lane];
        #pragma unroll
        for (int k = 0; k < EMB; ++k) acc = fmaf(z[k], gW1[(w*EMB + k)*EMB + lane], acc);
        sGH[w][lane] = ssp(acc);
    }
    __syncthreads();
    if (w < 3) {
        float acc2 = gb2[w*EMB + lane];
        #pragma unroll
        for (int k = 0; k < EMB; ++k) acc2 = fmaf(sGH[w][k], gW2[(w*EMB + k)*EMB + lane], acc2);
        sU[w][lane] = acc2;
    }
    __syncthreads();
    if (t < 64) upd[(size_t)blk*EMB + t] = sU[0][t] + sU[1][t] + sU[2][t];
}

extern "C" void kernel_launch(void* const* d_in, const int* in_sizes, int n_in,
                              void* d_out, int out_size, void* d_ws, size_t ws_size,
                              hipStream_t stream)
{
    const float* x   = (const float*)d_in[0];
    const float* Y   = (const float*)d_in[1];
    const float* eE  = (const float*)d_in[2];
    const float* eN  = (const float*)d_in[3];
    const float* wW1 = (const float*)d_in[4];
    const float* wb1 = (const float*)d_in[5];
    const float* wW2 = (const float*)d_in[6];
    const float* wb2 = (const float*)d_in[7];
    const float* hW1 = (const float*)d_in[8];
    const float* hb1 = (const float*)d_in[9];
    const float* hW2 = (const float*)d_in[10];
    const float* hb2 = (const float*)d_in[11];
    const float* gW1 = (const float*)d_in[12];
    const float* gb1 = (const float*)d_in[13];
    const float* gW2 = (const float*)d_in[14];
    const float* gb2 = (const float*)d_in[15];

    const int B   = in_sizes[0] / (NE * EMB);   // 256
    const int nbi = B * NE;                      // 16384

    float* hx = (float*)d_ws;                                     // 4 MB
    unsigned short* fr = (unsigned short*)((char*)d_ws + (size_t)nbi*EMB*4);

    float* upd     = (float*)d_out;
    float* out_el  = upd    + (size_t)nbi * EMB;
    float* out_nuc = out_el + (size_t)nbi * (NE-1) * EMB;

    k_wsplit<<<48,     256, 0, stream>>>(wW1, wW2, hW1, hW2, fr);
    k_hx    <<<nbi/64, 256, 0, stream>>>(x, hb1, hb2, fr, hx);
    k_main  <<<nbi,    256, 0, stream>>>(eE, eN, wb1, wb2, Y, hx,
                                         gW1, gb1, gW2, gb2, fr,
                                         out_el, out_nuc, upd);
}